// Round 12
// baseline (951.069 us; speedup 1.0000x reference)
//
#include <hip/hip_runtime.h>

typedef unsigned short u16;
typedef unsigned int u32;
typedef __attribute__((ext_vector_type(8))) short bf16x8;
typedef __attribute__((ext_vector_type(4))) float f32x4;
typedef __attribute__((ext_vector_type(16))) float f32x16;
typedef __attribute__((ext_vector_type(8))) unsigned short u16x8;
typedef __attribute__((ext_vector_type(4))) unsigned int u32x4;
typedef const __attribute__((address_space(1))) void gvoid;
typedef __attribute__((address_space(3))) void svoid;

#define T_TOK 100352
#define CDIM 256
#define ATTN_SCALE 0.17677669529663687f

__device__ __forceinline__ u16 f2bf(float f) {
    u32 u = __float_as_uint(f);
    u32 r = (u + 0x7fffu + ((u >> 16) & 1u)) >> 16;
    return (u16)r;
}
__device__ __forceinline__ float bf2f(u16 h) {
    return __uint_as_float(((u32)h) << 16);
}
__device__ __forceinline__ u32 cvtpk(float lo, float hi) {
    u32 r;
    asm("v_cvt_pk_bf16_f32 %0, %1, %2" : "=v"(r) : "v"(lo), "v"(hi));
    return r;
}
// tanh-form GELU: max abs dev from erf-form ~3e-4 (<< bf16 rounding of outputs)
__device__ __forceinline__ float gelu_f(float x) {
    float z = 0.7978845608028654f * (x + 0.044715f * x * x * x);
    float e = __expf(2.0f * z);
    float th = 1.0f - 2.0f * __builtin_amdgcn_rcpf(e + 1.0f);
    return 0.5f * x * (1.0f + th);
}
__device__ __forceinline__ int div7(int q) { return (q * 37) >> 8; }  // exact for 0..48
__device__ __forceinline__ int reg3(int r) { return r < 105 ? 0 : (r < 109 ? 1 : 2); }
__device__ __forceinline__ bf16x8 pack4(u32 a0, u32 a1, u32 a2, u32 a3) {
    u32x4 t; t.x = a0; t.y = a1; t.z = a2; t.w = a3;
    return __builtin_bit_cast(bf16x8, t);
}

// ---------------- fp32 -> bf16 weight conversion ----------------
__global__ void cvt_kernel(const float* __restrict__ in, u16* __restrict__ out, int n) {
    int i = blockIdx.x * 256 + threadIdx.x;
    if (i < n) out[i] = f2bf(in[i]);
}

// W1 [L][1024][256] -> granule-major per 32-hidden chunk: out[L][ch][g=32][r=32][e=8]
__global__ void cvt_w1_kernel(const float* __restrict__ in, u16* __restrict__ out) {
    int idx = blockIdx.x * 256 + threadIdx.x;     // 2*1024*256 total
    int e = idx & 7, r = (idx >> 3) & 31, g = (idx >> 8) & 31;
    int ch = (idx >> 13) & 31, L = idx >> 18;
    out[idx] = f2bf(in[(size_t)L*262144 + (ch*32 + r)*256 + g*8 + e]);
}
// W2 [L][256][1024] -> granule-major per 32-k chunk: out[L][ch][g=4][r=256][e=8]
__global__ void cvt_w2_kernel(const float* __restrict__ in, u16* __restrict__ out) {
    int idx = blockIdx.x * 256 + threadIdx.x;     // 2*1024*256 total
    int e = idx & 7, r = (idx >> 3) & 255, g = (idx >> 11) & 3;
    int ch = (idx >> 13) & 31, L = idx >> 18;
    out[idx] = f2bf(in[(size_t)L*262144 + r*1024 + ch*32 + g*8 + e]);
}

// ---------------- LayerNorm (fp32 in, bf16 out) ----------------
__global__ __launch_bounds__(256) void ln_kernel(
    const float* __restrict__ X, const float* __restrict__ w,
    const float* __restrict__ b, u16* __restrict__ Y)
{
    int wid = threadIdx.x >> 6, l = threadIdx.x & 63;
    int t = blockIdx.x * 4 + wid;
    const float4 x4 = ((const float4*)(X + (size_t)t * CDIM))[l];
    float s  = x4.x + x4.y + x4.z + x4.w;
    float s2 = x4.x*x4.x + x4.y*x4.y + x4.z*x4.z + x4.w*x4.w;
    #pragma unroll
    for (int o = 32; o; o >>= 1) { s += __shfl_xor(s, o); s2 += __shfl_xor(s2, o); }
    float mean = s * (1.0f/256.0f);
    float var  = s2 * (1.0f/256.0f) - mean*mean;
    float rstd = rsqrtf(var + 1e-5f);
    float4 w4 = ((const float4*)w)[l];
    float4 b4 = ((const float4*)b)[l];
    ushort4 o4;
    o4.x = f2bf((x4.x - mean)*rstd*w4.x + b4.x);
    o4.y = f2bf((x4.y - mean)*rstd*w4.y + b4.y);
    o4.z = f2bf((x4.z - mean)*rstd*w4.z + b4.z);
    o4.w = f2bf((x4.w - mean)*rstd*w4.w + b4.w);
    ((ushort4*)(Y + (size_t)t * CDIM))[l] = o4;
}

// ---------------- bf16 MFMA GEMM:  out[M,N] = A[M,K] @ B[N,K]^T + bias ----------------
template<int EPI>
__global__ __launch_bounds__(256) void gemm_kernel(
    const u16* __restrict__ A, const u16* __restrict__ Bw,
    const float* __restrict__ bias, void* __restrict__ outp,
    const float* __restrict__ res, int N, int K, int nTn)
{
    __shared__ __align__(16) char lds_raw[69632];   // staging 64KB; epilogue scratch 4x17KB (f32)
    u16 (*lds)[2][128 * 64] = (u16(*)[2][128 * 64])lds_raw;
    const int tid = threadIdx.x;
    const int l = tid & 63;
    const int w = tid >> 6;
    const int wr = w >> 1, wc = w & 1;

    const int nBlocks = gridDim.x;
    const int cpx = nBlocks >> 3;
    const int lin = (blockIdx.x & 7) * cpx + (blockIdx.x >> 3);
    const int nT = lin % nTn;
    const int mT = lin / nTn;

    f32x4 acc[4][4];
    #pragma unroll
    for (int m = 0; m < 4; ++m)
        #pragma unroll
        for (int n = 0; n < 4; ++n) acc[m][n] = (f32x4){0.f,0.f,0.f,0.f};

    const int sr = tid >> 3;
    const int sg = tid & 7;

    #define STAGE(buf, kt)                                                              \
        {                                                                               \
            _Pragma("unroll")                                                           \
            for (int c = 0; c < 4; ++c) {                                               \
                int r = c*32 + sr;                                                      \
                int gsrc = sg ^ (r & 7);                                                \
                const u16* ga = A  + (size_t)(mT*128 + r) * K + (kt) + gsrc*8;          \
                const u16* gb = Bw + (size_t)(nT*128 + r) * K + (kt) + gsrc*8;          \
                u16* la = &lds[buf][0][(c*256 + w*64) * 8];                              \
                u16* lb = &lds[buf][1][(c*256 + w*64) * 8];                              \
                __builtin_amdgcn_global_load_lds((gvoid*)ga, (svoid*)la, 16, 0, 0);     \
                __builtin_amdgcn_global_load_lds((gvoid*)gb, (svoid*)lb, 16, 0, 0);     \
            }                                                                           \
        }

    const int nSteps = K >> 6;
    int cur = 0;

    STAGE(0, 0);
    asm volatile("s_waitcnt vmcnt(0) lgkmcnt(0)" ::: "memory");
    __builtin_amdgcn_s_barrier();
    asm volatile("" ::: "memory");

    const int lr = l & 15, gq = l >> 4;
    for (int t = 0; t < nSteps; ++t) {
        bf16x8 a[2][4], b[2][4];
        #pragma unroll
        for (int kk = 0; kk < 2; ++kk) {
            #pragma unroll
            for (int m = 0; m < 4; ++m) {
                int r = wr*64 + m*16 + lr;
                int g = kk*4 + gq;
                a[kk][m] = *(const bf16x8*)&lds[cur][0][r*64 + (g ^ (r & 7))*8];
            }
            #pragma unroll
            for (int n = 0; n < 4; ++n) {
                int r = wc*64 + n*16 + lr;
                int g = kk*4 + gq;
                b[kk][n] = *(const bf16x8*)&lds[cur][1][r*64 + (g ^ (r & 7))*8];
            }
        }
        if (t + 1 < nSteps) STAGE(cur ^ 1, (t + 1) * 64);

        __builtin_amdgcn_s_setprio(1);
        #pragma unroll
        for (int kk = 0; kk < 2; ++kk)
            #pragma unroll
            for (int m = 0; m < 4; ++m)
                #pragma unroll
                for (int n = 0; n < 4; ++n)
                    acc[m][n] = __builtin_amdgcn_mfma_f32_16x16x32_bf16(a[kk][m], b[kk][n], acc[m][n], 0, 0, 0);
        __builtin_amdgcn_s_setprio(0);

        asm volatile("s_waitcnt vmcnt(0)" ::: "memory");
        __builtin_amdgcn_s_barrier();
        asm volatile("" ::: "memory");
        cur ^= 1;
    }
    #undef STAGE

    // ---- epilogue: wave-private f32 LDS transpose -> coalesced stores ----
    if (EPI == 2) {
        float* epf = (float*)lds_raw + w * (64 * 68);
        #pragma unroll
        for (int m = 0; m < 4; ++m)
            #pragma unroll
            for (int n = 0; n < 4; ++n) {
                float bb = bias[nT*128 + wc*64 + n*16 + lr];
                #pragma unroll
                for (int j = 0; j < 4; ++j)
                    epf[(m*16 + gq*4 + j)*68 + n*16 + lr] = acc[m][n][j] + bb;
            }
        const int rr4 = l >> 4, cc4 = (l & 15) * 4;
        float* outf = (float*)outp;
        #pragma unroll
        for (int p = 0; p < 16; ++p) {
            float4 vv = *(const float4*)&epf[(p*4 + rr4)*68 + cc4];
            size_t grow = (size_t)(mT*128 + wr*64 + p*4 + rr4);
            size_t gcol = (size_t)(nT*128 + wc*64 + cc4);
            float4 rv = *(const float4*)(res + grow*N + gcol);
            float4 ov; ov.x = vv.x + rv.x; ov.y = vv.y + rv.y;
            ov.z = vv.z + rv.z; ov.w = vv.w + rv.w;
            *(float4*)(outf + grow*N + gcol) = ov;
        }
    } else {
        float* epf = (float*)lds_raw + w * (64 * 68);
        #pragma unroll
        for (int m = 0; m < 4; ++m)
            #pragma unroll
            for (int n = 0; n < 4; ++n) {
                float bb = bias[nT*128 + wc*64 + n*16 + lr];
                #pragma unroll
                for (int j = 0; j < 4; ++j) {
                    float v = acc[m][n][j] + bb;
                    if (EPI == 1) v = gelu_f(v);
                    epf[(m*16 + gq*4 + j)*68 + n*16 + lr] = v;
                }
            }
        const int rr8 = l >> 3, cc8 = (l & 7) * 8;
        u16* outw = (u16*)outp;
        #pragma unroll
        for (int p = 0; p < 8; ++p) {
            float4 v0 = *(const float4*)&epf[(p*8 + rr8)*68 + cc8];
            float4 v1 = *(const float4*)&epf[(p*8 + rr8)*68 + cc8 + 4];
            u32x4 t;
            t.x = cvtpk(v0.x, v0.y); t.y = cvtpk(v0.z, v0.w);
            t.z = cvtpk(v1.x, v1.y); t.w = cvtpk(v1.z, v1.w);
            size_t grow = (size_t)(mT*128 + wr*64 + p*8 + rr8);
            size_t gcol = (size_t)(nT*128 + wc*64 + cc8);
            *(u16x8*)(outw + grow*N + gcol) = __builtin_bit_cast(u16x8, t);
        }
    }
}

// ---------------- fused LN2 + MLP: y=LN(x); xout = x + gelu(y W1^T + b1) W2^T + b2 ----
__global__ __launch_bounds__(256, 2) void mlp_kernel(
    const float* __restrict__ X, const float* __restrict__ lnw,
    const float* __restrict__ lnb, const u16* __restrict__ W1t,
    const float* __restrict__ B1, const u16* __restrict__ W2t,
    const float* __restrict__ B2, float* __restrict__ xout)
{
    __shared__ __align__(16) char lds_raw[69632];
    // [0,32768): buf0 (W1 16KB | W2 16KB), [32768,65536): buf1, [65536,69632): b1
    // epilogue reuse: 4 waves x 16640B scratch (32x130 f32)

    const int tid = threadIdx.x;
    const int l = tid & 63;
    const int w = tid >> 6;
    const int lo = l & 31;
    const int hi = l >> 5;
    const int row0 = blockIdx.x * 128 + w * 32;

    // ---- inline LN2: lane owns token row0+lo, channels kt*16 + hi*8 + [0,8) ----
    const float* xr = X + (size_t)(row0 + lo) * 256 + hi*8;
    float s = 0.f, s2 = 0.f;
    #pragma unroll
    for (int kt = 0; kt < 16; ++kt) {
        float4 a = *(const float4*)(xr + kt*16);
        float4 b = *(const float4*)(xr + kt*16 + 4);
        s  += (a.x + a.y) + (a.z + a.w) + (b.x + b.y) + (b.z + b.w);
        s2 += (a.x*a.x + a.y*a.y) + (a.z*a.z + a.w*a.w)
            + (b.x*b.x + b.y*b.y) + (b.z*b.z + b.w*b.w);
    }
    s  += __shfl_xor(s, 32);
    s2 += __shfl_xor(s2, 32);
    const float mean = s * (1.0f/256.0f);
    const float rstd = rsqrtf(s2 * (1.0f/256.0f) - mean*mean + 1e-5f);

    bf16x8 yf[16];
    #pragma unroll
    for (int kt = 0; kt < 16; ++kt) {
        float4 a = *(const float4*)(xr + kt*16);
        float4 b = *(const float4*)(xr + kt*16 + 4);
        float4 wa = *(const float4*)(lnw + kt*16 + hi*8);
        float4 wb = *(const float4*)(lnw + kt*16 + hi*8 + 4);
        float4 ba = *(const float4*)(lnb + kt*16 + hi*8);
        float4 bb = *(const float4*)(lnb + kt*16 + hi*8 + 4);
        float r0 = (a.x - mean)*rstd*wa.x + ba.x;
        float r1 = (a.y - mean)*rstd*wa.y + ba.y;
        float r2 = (a.z - mean)*rstd*wa.z + ba.z;
        float r3 = (a.w - mean)*rstd*wa.w + ba.w;
        float r4 = (b.x - mean)*rstd*wb.x + bb.x;
        float r5 = (b.y - mean)*rstd*wb.y + bb.y;
        float r6 = (b.z - mean)*rstd*wb.z + bb.z;
        float r7 = (b.w - mean)*rstd*wb.w + bb.w;
        yf[kt] = pack4(cvtpk(r0, r1), cvtpk(r2, r3), cvtpk(r4, r5), cvtpk(r6, r7));
    }

    // stage b1 to LDS
    ((float4*)(lds_raw + 65536))[tid] = ((const float4*)B1)[tid];

    f32x16 acc[8];
    #pragma unroll
    for (int ot = 0; ot < 8; ++ot) {
        f32x16 z;
        #pragma unroll
        for (int i = 0; i < 16; ++i) z[i] = 0.f;
        acc[ot] = z;
    }

    // identity-copy staging: 1024 granules each for W1/W2, layout matches LDS exactly
    #define MSTG(buf, ch)                                                                  \
        {                                                                                  \
            _Pragma("unroll")                                                              \
            for (int c = 0; c < 4; ++c) {                                                  \
                const u16* g1 = W1t + (size_t)(ch)*8192 + (c*256 + tid)*8;                 \
                u16* d1 = (u16*)(lds_raw + (buf)*32768 + (c*256 + w*64)*16);               \
                __builtin_amdgcn_global_load_lds((gvoid*)g1, (svoid*)d1, 16, 0, 0);        \
                const u16* g2 = W2t + (size_t)(ch)*8192 + (c*256 + tid)*8;                 \
                u16* d2 = (u16*)(lds_raw + (buf)*32768 + 16384 + (c*256 + w*64)*16);       \
                __builtin_amdgcn_global_load_lds((gvoid*)g2, (svoid*)d2, 16, 0, 0);        \
            }                                                                              \
        }

    MSTG(0, 0);
    asm volatile("s_waitcnt vmcnt(0) lgkmcnt(0)" ::: "memory");
    __builtin_amdgcn_s_barrier();
    asm volatile("" ::: "memory");

    #pragma unroll 1
    for (int ch = 0; ch < 32; ++ch) {
        const int cur = ch & 1;
        const char* w1b = lds_raw + cur*32768;
        const char* w2b = w1b + 16384;

        // prefetch next chunk first: drain at chunk end is covered by whole chunk
        if (ch + 1 < 32) MSTG(cur ^ 1, ch + 1);

        // ---- GEMM1: Ht (C col = token, row = hidden), 2-way split chain ----
        f32x16 ht0, ht1;
        #pragma unroll
        for (int i = 0; i < 16; ++i) { ht0[i] = 0.f; ht1[i] = 0.f; }
        #pragma unroll
        for (int kt = 0; kt < 16; kt += 2) {
            bf16x8 w1f0 = *(const bf16x8*)(w1b + (2*kt + hi)*512 + lo*16);
            bf16x8 w1f1 = *(const bf16x8*)(w1b + (2*kt + 2 + hi)*512 + lo*16);
            ht0 = __builtin_amdgcn_mfma_f32_32x32x16_bf16(w1f0, yf[kt], ht0, 0, 0, 0);
            ht1 = __builtin_amdgcn_mfma_f32_32x32x16_bf16(w1f1, yf[kt+1], ht1, 0, 0, 0);
        }

        // ---- bias + gelu (elementwise, C-layout) ----
        const float* b1l = (const float*)(lds_raw + 65536) + ch*32;
        f32x16 ht;
        #pragma unroll
        for (int i = 0; i < 16; ++i) {
            int r = (i & 3) + 8*(i >> 2) + 4*hi;
            ht[i] = gelu_f(ht0[i] + ht1[i] + b1l[r]);
        }

        // ---- repack to A-fragments (m = token, k = hidden), pure-register ----
        u32 p0 = cvtpk(ht[0], ht[1]),  p1 = cvtpk(ht[2], ht[3]);
        u32 p2 = cvtpk(ht[4], ht[5]),  p3 = cvtpk(ht[6], ht[7]);
        u32 p4 = cvtpk(ht[8], ht[9]),  p5 = cvtpk(ht[10], ht[11]);
        u32 p6 = cvtpk(ht[12], ht[13]), p7 = cvtpk(ht[14], ht[15]);
        asm volatile("v_permlane32_swap_b32 %0, %1" : "+v"(p0), "+v"(p2));
        asm volatile("v_permlane32_swap_b32 %0, %1" : "+v"(p1), "+v"(p3));
        asm volatile("v_permlane32_swap_b32 %0, %1" : "+v"(p4), "+v"(p6));
        asm volatile("v_permlane32_swap_b32 %0, %1" : "+v"(p5), "+v"(p7));
        bf16x8 pa0 = pack4(p0, p1, p2, p3);
        bf16x8 pa1 = pack4(p4, p5, p6, p7);

        // ---- GEMM2: acc[ot] += pa @ W2chunk^T ----
        __builtin_amdgcn_s_setprio(1);
        #pragma unroll
        for (int ot = 0; ot < 8; ++ot) {
            bf16x8 w2f0 = *(const bf16x8*)(w2b + (hi)*4096 + (ot*32 + lo)*16);
            bf16x8 w2f1 = *(const bf16x8*)(w2b + (2 + hi)*4096 + (ot*32 + lo)*16);
            acc[ot] = __builtin_amdgcn_mfma_f32_32x32x16_bf16(pa0, w2f0, acc[ot], 0, 0, 0);
            acc[ot] = __builtin_amdgcn_mfma_f32_32x32x16_bf16(pa1, w2f1, acc[ot], 0, 0, 0);
        }
        __builtin_amdgcn_s_setprio(0);

        asm volatile("s_waitcnt vmcnt(0)" ::: "memory");
        __builtin_amdgcn_s_barrier();
        asm volatile("" ::: "memory");
    }
    #undef MSTG

    // ---- epilogue: wave-private transpose -> coalesced float4 +res stores ----
    float b2v[8];
    #pragma unroll
    for (int ot = 0; ot < 8; ++ot) b2v[ot] = B2[ot*32 + lo];

    float* scr = (float*)(lds_raw + w * 16640);   // 32 rows x 130 f32
    #pragma unroll 1
    for (int half = 0; half < 2; ++half) {
        #pragma unroll
        for (int ot4 = 0; ot4 < 4; ++ot4) {
            int ot = half*4 + ot4;
            #pragma unroll
            for (int i = 0; i < 16; ++i) {
                int r = (i & 3) + 8*(i >> 2) + 4*hi;
                scr[r*130 + ot4*32 + lo] = acc[ot][i] + b2v[ot];
            }
        }
        asm volatile("s_waitcnt lgkmcnt(0)" ::: "memory");
        __builtin_amdgcn_sched_barrier(0);
        const int rr = l >> 5, cc = (l & 31) * 4;   // full 32x128 coverage
        #pragma unroll
        for (int p = 0; p < 16; ++p) {
            float4 vv = *(const float4*)&scr[(p*2 + rr)*130 + cc];
            size_t off = (size_t)(row0 + p*2 + rr) * 256 + half*128 + cc;
            float4 rv = *(const float4*)(X + off);
            float4 ov; ov.x = vv.x + rv.x; ov.y = vv.y + rv.y;
            ov.z = vv.z + rv.z; ov.w = vv.w + rv.w;
            *(float4*)(xout + off) = ov;
        }
        asm volatile("s_waitcnt lgkmcnt(0)" ::: "memory");
        __builtin_amdgcn_sched_barrier(0);
    }
}

// ---------------- MFMA windowed attention, swapped-QK^T 32x32 ----------------
__global__ __launch_bounds__(256) void attn_kernel(
    const u16* __restrict__ qkv, const float* __restrict__ rpb,
    u16* __restrict__ outb, int shift)
{
    __shared__ u16 Vt[8][2048];       // head h: Vt[h][d*64 + (k ^ ((d&7)<<3))]
    __shared__ float biasl[8 * 176];
    __shared__ int tok[64];

    const int t = threadIdx.x;
    const int w = t >> 6;
    const int l = t & 63;
    const int lo = l & 31;
    const int hi = l >> 5;
    const int win = blockIdx.x;
    const int wj = win & 15, wi = (win >> 4) & 15, bb = win >> 8;

    if (t < 64) {
        int qq = t > 48 ? 48 : t;
        int i = div7(qq), j = qq - i*7;
        int rr = wi*7 + i + shift; if (rr >= 112) rr -= 112;
        int cc = wj*7 + j + shift; if (cc >= 112) cc -= 112;
        tok[t] = bb*12544 + rr*112 + cc;
    }
    for (int i2 = t; i2 < 1352; i2 += 256)
        biasl[(i2 & 7)*176 + (i2 >> 3)] = rpb[i2];
    __syncthreads();

    int iqv[2], jqv[2], regq[2];
    #pragma unroll
    for (int nt = 0; nt < 2; ++nt) {
        int q = nt*32 + lo; int qb = q > 48 ? 48 : q;
        int iq = div7(qb), jq = qb - iq*7;
        iqv[nt] = iq; jqv[nt] = jq;
        regq[nt] = 0;
        if (shift > 0) regq[nt] = reg3(wi*7 + iq)*3 + reg3(wj*7 + jq);
    }

    #pragma unroll 1
    for (int hh = 0; hh < 2; ++hh) {
        const int h = 2*w + hh;

        {
            u16x8 vreg[4];
            if (l < 49) {
                const u16x8* vs = (const u16x8*)(qkv + (size_t)tok[l]*768 + 512 + h*32);
                #pragma unroll
                for (int c4 = 0; c4 < 4; ++c4) vreg[c4] = vs[c4];
            } else {
                #pragma unroll
                for (int c4 = 0; c4 < 4; ++c4) vreg[c4] = (u16x8){0,0,0,0,0,0,0,0};
            }
            u16* vt = &Vt[h][0];
            #pragma unroll
            for (int c4 = 0; c4 < 4; ++c4)
                #pragma unroll
                for (int e = 0; e < 8; ++e)
                    vt[(c4*8 + e)*64 + (l ^ (e << 3))] = vreg[c4][e];
        }

        bf16x8 kf[2][2], qf[2][2];
        #pragma unroll
        for (int mt = 0; mt < 2; ++mt)
            #pragma unroll
            for (int td = 0; td < 2; ++td)
                kf[mt][td] = *(const bf16x8*)(qkv + (size_t)tok[mt*32 + lo]*768 + 256 + h*32 + td*16 + hi*8);
        #pragma unroll
        for (int nt = 0; nt < 2; ++nt)
            #pragma unroll
            for (int td = 0; td < 2; ++td)
                qf[nt][td] = *(const bf16x8*)(qkv + (size_t)tok[nt*32 + lo]*768 + h*32 + td*16 + hi*8);

        f32x16 s[2][2];
        #pragma unroll
        for (int mt = 0; mt < 2; ++mt)
            #pragma unroll
            for (int nt = 0; nt < 2; ++nt) {
                f32x16 z;
                #pragma unroll
                for (int i = 0; i < 16; ++i) z[i] = 0.f;
                s[mt][nt] = z;
            }
        #pragma unroll
        for (int td = 0; td < 2; ++td)
            #pragma unroll
            for (int mt = 0; mt < 2; ++mt)
                #pragma unroll
                for (int nt = 0; nt < 2; ++nt)
                    s[mt][nt] = __builtin_amdgcn_mfma_f32_32x32x16_bf16(kf[mt][td], qf[nt][td], s[mt][nt], 0, 0, 0);

        asm volatile("s_waitcnt lgkmcnt(0)" ::: "memory");
        __builtin_amdgcn_sched_barrier(0);

        const float* bh = biasl + h*176;
        #pragma unroll
        for (int mt = 0; mt < 2; ++mt) {
            #pragma unroll
            for (int i = 0; i < 16; ++i) {
                int r = (i & 3) + 8*(i >> 2) + 4*hi;
                int k = mt*32 + r;
                bool valid = k < 49;
                int kb = valid ? k : 48;
                int ik = div7(kb), jk = kb - ik*7;
                int regk = 0;
                if (shift > 0) regk = reg3(wi*7 + ik)*3 + reg3(wj*7 + jk);
                #pragma unroll
                for (int nt = 0; nt < 2; ++nt) {
                    float v = s[mt][nt][i] * ATTN_SCALE
                            + bh[(iqv[nt] - ik + 6)*13 + (jqv[nt] - jk + 6)];
                    if (shift > 0 && regq[nt] != regk) v -= 100.0f;
                    if (!valid) v = -1e30f;
                    s[mt][nt][i] = v;
                }
            }
        }

        #pragma unroll
        for (int nt = 0; nt < 2; ++nt) {
            float mx = -1e30f;
            #pragma unroll
            for (int i = 0; i < 16; ++i) mx = fmaxf(mx, fmaxf(s[0][nt][i], s[1][nt][i]));
            mx = fmaxf(mx, __shfl_xor(mx, 32));
            float sum = 0.f;
            #pragma unroll
            for (int mt = 0; mt < 2; ++mt)
                #pragma unroll
                for (int i = 0; i < 16; ++i) {
                    float e = __expf(s[mt][nt][i] - mx);
                    s[mt][nt][i] = e;
                    sum += e;
                }
            sum += __shfl_xor(sum, 32);
            float inv = __builtin_amdgcn_rcpf(sum);

            f32x16 o;
            #pragma unroll
            for (int i = 0; i < 16; ++i) o[i] = 0.f;
            #pragma unroll
            for (int mt = 0; mt < 2; ++mt) {
                u32 q0 = cvtpk(s[mt][nt][0]*inv,  s[mt][nt][1]*inv);
                u32 q1 = cvtpk(s[mt][nt][2]*inv,  s[mt][nt][3]*inv);
                u32 q2 = cvtpk(s[mt][nt][4]*inv,  s[mt][nt][5]*inv);
                u32 q3 = cvtpk(s[mt][nt][6]*inv,  s[mt][nt][7]*inv);
                u32 q4 = cvtpk(s[mt][nt][8]*inv,  s[mt][nt][9]*inv);
                u32 q5 = cvtpk(s[mt][nt][10]*inv, s[mt][nt][11]*inv);
                u32 q6 = cvtpk(s[mt][nt][12]*inv, s[mt][nt][13]*inv);
                u32 q7 = cvtpk(s[mt][nt][14]*inv, s[mt][nt][15]*inv);
                asm volatile("v_permlane32_swap_b32 %0, %1" : "+v"(q0), "+v"(q2));
                asm volatile("v_permlane32_swap_b32 %0, %1" : "+v"(q1), "+v"(q3));
                asm volatile("v_permlane32_swap_b32 %0, %1" : "+v"(q4), "+v"(q6));
                asm volatile("v_permlane32_swap_b32 %0, %1" : "+v"(q5), "+v"(q7));
                bf16x8 pf0 = pack4(q0, q1, q2, q3);
                bf16x8 pf1 = pack4(q4, q5, q6, q7);
                bf16x8 vb0 = *(const bf16x8*)(&Vt[h][lo*64 + (((mt*2+0)*16 + hi*8) ^ ((lo & 7) << 3))]);
                bf16x8 vb1 = *(const bf16x8*)(&Vt[h][lo*64 + (((mt*2+1)*16 + hi*8) ^ ((lo & 7) << 3))]);
                o = __builtin_amdgcn_mfma_f32_32x32x16_bf16(pf0, vb0, o, 0, 0, 0);
                o = __builtin_amdgcn_mfma_f32_32x32x16_bf16(pf1, vb1, o, 0, 0, 0);
            }

            #pragma unroll
            for (int i = 0; i < 16; ++i) {
                int q = nt*32 + (i & 3) + 8*(i >> 2) + 4*hi;
                if (q < 49)
                    outb[(size_t)tok[q]*256 + h*32 + lo] = f2bf(o[i]);
            }
        }
    }
}

// ---------------- host ----------------
extern "C" void kernel_launch(void* const* d_in, const int* in_sizes, int n_in,
                              void* d_out, int out_size, void* d_ws, size_t ws_size,
                              hipStream_t stream) {
    const float* x_in   = (const float*)d_in[0];
    const float* ln1_w  = (const float*)d_in[1];
    const float* ln1_b  = (const float*)d_in[2];
    const float* qkv_w  = (const float*)d_in[3];
    const float* qkv_b  = (const float*)d_in[4];
    const float* proj_w = (const float*)d_in[5];
    const float* proj_b = (const float*)d_in[6];
    const float* rpb    = (const float*)d_in[7];
    const float* ln2_w  = (const float*)d_in[8];
    const float* ln2_b  = (const float*)d_in[9];
    const float* mlp_w1 = (const float*)d_in[10];
    const float* mlp_b1 = (const float*)d_in[11];
    const float* mlp_w2 = (const float*)d_in[12];
    const float* mlp_b2 = (const float*)d_in[13];
    float* xout = (float*)d_out;

    char* p = (char*)d_ws;
    u16* wq = (u16*)p;  p += (size_t)2*768*256*2;
    u16* wp = (u16*)p;  p += (size_t)2*256*256*2;
    u16* w1t = (u16*)p; p += (size_t)2*1024*256*2;
    u16* w2t = (u16*)p; p += (size_t)2*256*1024*2;
    u16* buf_y   = (u16*)p; p += (size_t)T_TOK*256*2;
    u16* buf_big = (u16*)p;

    {
        int n;
        n = 2*768*256;  cvt_kernel<<<(n+255)/256, 256, 0, stream>>>(qkv_w,  wq, n);
        n = 2*256*256;  cvt_kernel<<<(n+255)/256, 256, 0, stream>>>(proj_w, wp, n);
        cvt_w1_kernel<<<2048, 256, 0, stream>>>(mlp_w1, w1t);
        cvt_w2_kernel<<<2048, 256, 0, stream>>>(mlp_w2, w2t);
    }

    for (int i = 0; i < 2; ++i) {
        const int shift = (i == 0) ? 0 : 3;
        const float* xcur = (i == 0) ? x_in : xout;

        ln_kernel<<<T_TOK/4, 256, 0, stream>>>(xcur, ln1_w + i*256, ln1_b + i*256, buf_y);
        gemm_kernel<0><<<784*6, 256, 0, stream>>>(
            buf_y, wq + (size_t)i*768*256, qkv_b + i*768, buf_big, nullptr, 768, 256, 6);
        attn_kernel<<<2048, 256, 0, stream>>>(buf_big, rpb + i*169*8, buf_y, shift);
        gemm_kernel<2><<<784*2, 256, 0, stream>>>(
            buf_y, wp + (size_t)i*256*256, proj_b + i*256, xout, xcur, 256, 256, 2);
        // fused LN2 + MLP (reads x from xout, writes xout)
        mlp_kernel<<<784, 256, 0, stream>>>(
            xout, ln2_w + i*256, ln2_b + i*256,
            w1t + (size_t)i*262144, mlp_b1 + i*1024,
            w2t + (size_t)i*262144, mlp_b2 + i*256, xout);
    }
}

// Round 13
// 929.471 us; speedup vs baseline: 1.0232x; 1.0232x over previous
//
#include <hip/hip_runtime.h>

typedef unsigned short u16;
typedef unsigned int u32;
typedef __attribute__((ext_vector_type(8))) short bf16x8;
typedef __attribute__((ext_vector_type(4))) float f32x4;
typedef __attribute__((ext_vector_type(16))) float f32x16;
typedef __attribute__((ext_vector_type(8))) unsigned short u16x8;
typedef __attribute__((ext_vector_type(4))) unsigned int u32x4;
typedef const __attribute__((address_space(1))) void gvoid;
typedef __attribute__((address_space(3))) void svoid;

#define T_TOK 100352
#define CDIM 256
#define ATTN_SCALE 0.17677669529663687f

__device__ __forceinline__ u16 f2bf(float f) {
    u32 u = __float_as_uint(f);
    u32 r = (u + 0x7fffu + ((u >> 16) & 1u)) >> 16;
    return (u16)r;
}
__device__ __forceinline__ float bf2f(u16 h) {
    return __uint_as_float(((u32)h) << 16);
}
__device__ __forceinline__ u32 cvtpk(float lo, float hi) {
    u32 r;
    asm("v_cvt_pk_bf16_f32 %0, %1, %2" : "=v"(r) : "v"(lo), "v"(hi));
    return r;
}
// tanh-form GELU: max abs dev from erf-form ~3e-4 (<< bf16 rounding of outputs)
__device__ __forceinline__ float gelu_f(float x) {
    float z = 0.7978845608028654f * (x + 0.044715f * x * x * x);
    float e = __expf(2.0f * z);
    float th = 1.0f - 2.0f * __builtin_amdgcn_rcpf(e + 1.0f);
    return 0.5f * x * (1.0f + th);
}
__device__ __forceinline__ int div7(int q) { return (q * 37) >> 8; }  // exact for 0..48
__device__ __forceinline__ int reg3(int r) { return r < 105 ? 0 : (r < 109 ? 1 : 2); }
__device__ __forceinline__ bf16x8 pack4(u32 a0, u32 a1, u32 a2, u32 a3) {
    u32x4 t; t.x = a0; t.y = a1; t.z = a2; t.w = a3;
    return __builtin_bit_cast(bf16x8, t);
}

// ---------------- fp32 -> bf16 weight conversion ----------------
__global__ void cvt_kernel(const float* __restrict__ in, u16* __restrict__ out, int n) {
    int i = blockIdx.x * 256 + threadIdx.x;
    if (i < n) out[i] = f2bf(in[i]);
}

// W1 [L][1024][256] -> granule-major per 32-hidden chunk: out[L][ch][g=32][r=32][e=8]
__global__ void cvt_w1_kernel(const float* __restrict__ in, u16* __restrict__ out) {
    int idx = blockIdx.x * 256 + threadIdx.x;     // 2*1024*256 total
    int e = idx & 7, r = (idx >> 3) & 31, g = (idx >> 8) & 31;
    int ch = (idx >> 13) & 31, L = idx >> 18;
    out[idx] = f2bf(in[(size_t)L*262144 + (ch*32 + r)*256 + g*8 + e]);
}
// W2 [L][256][1024] -> granule-major per 32-k chunk: out[L][ch][g=4][r=256][e=8]
__global__ void cvt_w2_kernel(const float* __restrict__ in, u16* __restrict__ out) {
    int idx = blockIdx.x * 256 + threadIdx.x;     // 2*1024*256 total
    int e = idx & 7, r = (idx >> 3) & 255, g = (idx >> 11) & 3;
    int ch = (idx >> 13) & 31, L = idx >> 18;
    out[idx] = f2bf(in[(size_t)L*262144 + r*1024 + ch*32 + g*8 + e]);
}

// ---------------- LayerNorm (fp32 in, bf16 out) ----------------
__global__ __launch_bounds__(256) void ln_kernel(
    const float* __restrict__ X, const float* __restrict__ w,
    const float* __restrict__ b, u16* __restrict__ Y)
{
    int wid = threadIdx.x >> 6, l = threadIdx.x & 63;
    int t = blockIdx.x * 4 + wid;
    const float4 x4 = ((const float4*)(X + (size_t)t * CDIM))[l];
    float s  = x4.x + x4.y + x4.z + x4.w;
    float s2 = x4.x*x4.x + x4.y*x4.y + x4.z*x4.z + x4.w*x4.w;
    #pragma unroll
    for (int o = 32; o; o >>= 1) { s += __shfl_xor(s, o); s2 += __shfl_xor(s2, o); }
    float mean = s * (1.0f/256.0f);
    float var  = s2 * (1.0f/256.0f) - mean*mean;
    float rstd = rsqrtf(var + 1e-5f);
    float4 w4 = ((const float4*)w)[l];
    float4 b4 = ((const float4*)b)[l];
    ushort4 o4;
    o4.x = f2bf((x4.x - mean)*rstd*w4.x + b4.x);
    o4.y = f2bf((x4.y - mean)*rstd*w4.y + b4.y);
    o4.z = f2bf((x4.z - mean)*rstd*w4.z + b4.z);
    o4.w = f2bf((x4.w - mean)*rstd*w4.w + b4.w);
    ((ushort4*)(Y + (size_t)t * CDIM))[l] = o4;
}

// ---------------- bf16 MFMA GEMM:  out[M,N] = A[M,K] @ B[N,K]^T + bias ----------------
template<int EPI>
__global__ __launch_bounds__(256) void gemm_kernel(
    const u16* __restrict__ A, const u16* __restrict__ Bw,
    const float* __restrict__ bias, void* __restrict__ outp,
    const float* __restrict__ res, int N, int K, int nTn)
{
    __shared__ __align__(16) char lds_raw[69632];   // staging 64KB; epilogue scratch 4x17KB (f32)
    u16 (*lds)[2][128 * 64] = (u16(*)[2][128 * 64])lds_raw;
    const int tid = threadIdx.x;
    const int l = tid & 63;
    const int w = tid >> 6;
    const int wr = w >> 1, wc = w & 1;

    const int nBlocks = gridDim.x;
    const int cpx = nBlocks >> 3;
    const int lin = (blockIdx.x & 7) * cpx + (blockIdx.x >> 3);
    const int nT = lin % nTn;
    const int mT = lin / nTn;

    f32x4 acc[4][4];
    #pragma unroll
    for (int m = 0; m < 4; ++m)
        #pragma unroll
        for (int n = 0; n < 4; ++n) acc[m][n] = (f32x4){0.f,0.f,0.f,0.f};

    const int sr = tid >> 3;
    const int sg = tid & 7;

    #define STAGE(buf, kt)                                                              \
        {                                                                               \
            _Pragma("unroll")                                                           \
            for (int c = 0; c < 4; ++c) {                                               \
                int r = c*32 + sr;                                                      \
                int gsrc = sg ^ (r & 7);                                                \
                const u16* ga = A  + (size_t)(mT*128 + r) * K + (kt) + gsrc*8;          \
                const u16* gb = Bw + (size_t)(nT*128 + r) * K + (kt) + gsrc*8;          \
                u16* la = &lds[buf][0][(c*256 + w*64) * 8];                              \
                u16* lb = &lds[buf][1][(c*256 + w*64) * 8];                              \
                __builtin_amdgcn_global_load_lds((gvoid*)ga, (svoid*)la, 16, 0, 0);     \
                __builtin_amdgcn_global_load_lds((gvoid*)gb, (svoid*)lb, 16, 0, 0);     \
            }                                                                           \
        }

    const int nSteps = K >> 6;
    int cur = 0;

    STAGE(0, 0);
    asm volatile("s_waitcnt vmcnt(0) lgkmcnt(0)" ::: "memory");
    __builtin_amdgcn_s_barrier();
    asm volatile("" ::: "memory");

    const int lr = l & 15, gq = l >> 4;
    for (int t = 0; t < nSteps; ++t) {
        bf16x8 a[2][4], b[2][4];
        #pragma unroll
        for (int kk = 0; kk < 2; ++kk) {
            #pragma unroll
            for (int m = 0; m < 4; ++m) {
                int r = wr*64 + m*16 + lr;
                int g = kk*4 + gq;
                a[kk][m] = *(const bf16x8*)&lds[cur][0][r*64 + (g ^ (r & 7))*8];
            }
            #pragma unroll
            for (int n = 0; n < 4; ++n) {
                int r = wc*64 + n*16 + lr;
                int g = kk*4 + gq;
                b[kk][n] = *(const bf16x8*)&lds[cur][1][r*64 + (g ^ (r & 7))*8];
            }
        }
        if (t + 1 < nSteps) STAGE(cur ^ 1, (t + 1) * 64);

        __builtin_amdgcn_s_setprio(1);
        #pragma unroll
        for (int kk = 0; kk < 2; ++kk)
            #pragma unroll
            for (int m = 0; m < 4; ++m)
                #pragma unroll
                for (int n = 0; n < 4; ++n)
                    acc[m][n] = __builtin_amdgcn_mfma_f32_16x16x32_bf16(a[kk][m], b[kk][n], acc[m][n], 0, 0, 0);
        __builtin_amdgcn_s_setprio(0);

        asm volatile("s_waitcnt vmcnt(0)" ::: "memory");
        __builtin_amdgcn_s_barrier();
        asm volatile("" ::: "memory");
        cur ^= 1;
    }
    #undef STAGE

    // ---- epilogue: wave-private f32 LDS transpose -> coalesced stores ----
    if (EPI == 2) {
        float* epf = (float*)lds_raw + w * (64 * 68);
        #pragma unroll
        for (int m = 0; m < 4; ++m)
            #pragma unroll
            for (int n = 0; n < 4; ++n) {
                float bb = bias[nT*128 + wc*64 + n*16 + lr];
                #pragma unroll
                for (int j = 0; j < 4; ++j)
                    epf[(m*16 + gq*4 + j)*68 + n*16 + lr] = acc[m][n][j] + bb;
            }
        const int rr4 = l >> 4, cc4 = (l & 15) * 4;
        float* outf = (float*)outp;
        #pragma unroll
        for (int p = 0; p < 16; ++p) {
            float4 vv = *(const float4*)&epf[(p*4 + rr4)*68 + cc4];
            size_t grow = (size_t)(mT*128 + wr*64 + p*4 + rr4);
            size_t gcol = (size_t)(nT*128 + wc*64 + cc4);
            float4 rv = *(const float4*)(res + grow*N + gcol);
            float4 ov; ov.x = vv.x + rv.x; ov.y = vv.y + rv.y;
            ov.z = vv.z + rv.z; ov.w = vv.w + rv.w;
            *(float4*)(outf + grow*N + gcol) = ov;
        }
    } else {
        float* epf = (float*)lds_raw + w * (64 * 68);
        #pragma unroll
        for (int m = 0; m < 4; ++m)
            #pragma unroll
            for (int n = 0; n < 4; ++n) {
                float bb = bias[nT*128 + wc*64 + n*16 + lr];
                #pragma unroll
                for (int j = 0; j < 4; ++j) {
                    float v = acc[m][n][j] + bb;
                    if (EPI == 1) v = gelu_f(v);
                    epf[(m*16 + gq*4 + j)*68 + n*16 + lr] = v;
                }
            }
        const int rr8 = l >> 3, cc8 = (l & 7) * 8;
        u16* outw = (u16*)outp;
        #pragma unroll
        for (int p = 0; p < 8; ++p) {
            float4 v0 = *(const float4*)&epf[(p*8 + rr8)*68 + cc8];
            float4 v1 = *(const float4*)&epf[(p*8 + rr8)*68 + cc8 + 4];
            u32x4 t;
            t.x = cvtpk(v0.x, v0.y); t.y = cvtpk(v0.z, v0.w);
            t.z = cvtpk(v1.x, v1.y); t.w = cvtpk(v1.z, v1.w);
            size_t grow = (size_t)(mT*128 + wr*64 + p*8 + rr8);
            size_t gcol = (size_t)(nT*128 + wc*64 + cc8);
            *(u16x8*)(outw + grow*N + gcol) = __builtin_bit_cast(u16x8, t);
        }
    }
}

// ---------------- fused LN2 + MLP: y=LN(x); xout = x + gelu(y W1^T + b1) W2^T + b2 ----
// Register budget note: yf(64) + acc(128) + ht(16) + temps must stay under the
// 256-reg unified-file cap at 2 waves/SIMD -- the R8-R12 ht0/ht1 split chain
// pushed peak live to ~250 and spilled ~1KB/thread per loop (WRITE_SIZE 3x).
__global__ __launch_bounds__(256, 2) void mlp_kernel(
    const float* __restrict__ X, const float* __restrict__ lnw,
    const float* __restrict__ lnb, const u16* __restrict__ W1t,
    const float* __restrict__ B1, const u16* __restrict__ W2t,
    const float* __restrict__ B2, float* __restrict__ xout)
{
    __shared__ __align__(16) char lds_raw[69632];
    // [0,32768): buf0 (W1 16KB | W2 16KB), [32768,65536): buf1, [65536,69632): b1
    // epilogue reuse: 4 waves x 16640B scratch (32x130 f32)

    const int tid = threadIdx.x;
    const int l = tid & 63;
    const int w = tid >> 6;
    const int lo = l & 31;
    const int hi = l >> 5;
    const int row0 = blockIdx.x * 128 + w * 32;

    // ---- inline LN2: lane owns token row0+lo, channels kt*16 + hi*8 + [0,8) ----
    const float* xr = X + (size_t)(row0 + lo) * 256 + hi*8;
    float s = 0.f, s2 = 0.f;
    #pragma unroll
    for (int kt = 0; kt < 16; ++kt) {
        float4 a = *(const float4*)(xr + kt*16);
        float4 b = *(const float4*)(xr + kt*16 + 4);
        s  += (a.x + a.y) + (a.z + a.w) + (b.x + b.y) + (b.z + b.w);
        s2 += (a.x*a.x + a.y*a.y) + (a.z*a.z + a.w*a.w)
            + (b.x*b.x + b.y*b.y) + (b.z*b.z + b.w*b.w);
    }
    s  += __shfl_xor(s, 32);
    s2 += __shfl_xor(s2, 32);
    const float mean = s * (1.0f/256.0f);
    const float rstd = rsqrtf(s2 * (1.0f/256.0f) - mean*mean + 1e-5f);

    bf16x8 yf[16];
    #pragma unroll
    for (int kt = 0; kt < 16; ++kt) {
        float4 a = *(const float4*)(xr + kt*16);
        float4 b = *(const float4*)(xr + kt*16 + 4);
        float4 wa = *(const float4*)(lnw + kt*16 + hi*8);
        float4 wb = *(const float4*)(lnw + kt*16 + hi*8 + 4);
        float4 ba = *(const float4*)(lnb + kt*16 + hi*8);
        float4 bb = *(const float4*)(lnb + kt*16 + hi*8 + 4);
        float r0 = (a.x - mean)*rstd*wa.x + ba.x;
        float r1 = (a.y - mean)*rstd*wa.y + ba.y;
        float r2 = (a.z - mean)*rstd*wa.z + ba.z;
        float r3 = (a.w - mean)*rstd*wa.w + ba.w;
        float r4 = (b.x - mean)*rstd*wb.x + bb.x;
        float r5 = (b.y - mean)*rstd*wb.y + bb.y;
        float r6 = (b.z - mean)*rstd*wb.z + bb.z;
        float r7 = (b.w - mean)*rstd*wb.w + bb.w;
        yf[kt] = pack4(cvtpk(r0, r1), cvtpk(r2, r3), cvtpk(r4, r5), cvtpk(r6, r7));
    }

    // stage b1 to LDS
    ((float4*)(lds_raw + 65536))[tid] = ((const float4*)B1)[tid];

    f32x16 acc[8];
    #pragma unroll
    for (int ot = 0; ot < 8; ++ot) {
        f32x16 z;
        #pragma unroll
        for (int i = 0; i < 16; ++i) z[i] = 0.f;
        acc[ot] = z;
    }

    // identity-copy staging: 1024 granules each for W1/W2, layout matches LDS exactly
    #define MSTG(buf, ch)                                                                  \
        {                                                                                  \
            _Pragma("unroll")                                                              \
            for (int c = 0; c < 4; ++c) {                                                  \
                const u16* g1 = W1t + (size_t)(ch)*8192 + (c*256 + tid)*8;                 \
                u16* d1 = (u16*)(lds_raw + (buf)*32768 + (c*256 + w*64)*16);               \
                __builtin_amdgcn_global_load_lds((gvoid*)g1, (svoid*)d1, 16, 0, 0);        \
                const u16* g2 = W2t + (size_t)(ch)*8192 + (c*256 + tid)*8;                 \
                u16* d2 = (u16*)(lds_raw + (buf)*32768 + 16384 + (c*256 + w*64)*16);       \
                __builtin_amdgcn_global_load_lds((gvoid*)g2, (svoid*)d2, 16, 0, 0);        \
            }                                                                              \
        }

    MSTG(0, 0);
    asm volatile("s_waitcnt vmcnt(0) lgkmcnt(0)" ::: "memory");
    __builtin_amdgcn_s_barrier();
    asm volatile("" ::: "memory");

    #pragma unroll 1
    for (int ch = 0; ch < 32; ++ch) {
        const int cur = ch & 1;
        const char* w1b = lds_raw + cur*32768;
        const char* w2b = w1b + 16384;

        // prefetch next chunk first: drain at chunk end is covered by whole chunk
        if (ch + 1 < 32) MSTG(cur ^ 1, ch + 1);

        // ---- GEMM1: Ht (C col = token, row = hidden), single accumulator ----
        f32x16 ht;
        #pragma unroll
        for (int i = 0; i < 16; ++i) ht[i] = 0.f;
        #pragma unroll
        for (int kt = 0; kt < 16; ++kt) {
            bf16x8 w1f = *(const bf16x8*)(w1b + (2*kt + hi)*512 + lo*16);
            ht = __builtin_amdgcn_mfma_f32_32x32x16_bf16(w1f, yf[kt], ht, 0, 0, 0);
        }

        // ---- bias + gelu (elementwise, C-layout, in place) ----
        const float* b1l = (const float*)(lds_raw + 65536) + ch*32;
        #pragma unroll
        for (int i = 0; i < 16; ++i) {
            int r = (i & 3) + 8*(i >> 2) + 4*hi;
            ht[i] = gelu_f(ht[i] + b1l[r]);
        }

        // ---- repack to A-fragments (m = token, k = hidden), pure-register ----
        u32 p0 = cvtpk(ht[0], ht[1]),  p1 = cvtpk(ht[2], ht[3]);
        u32 p2 = cvtpk(ht[4], ht[5]),  p3 = cvtpk(ht[6], ht[7]);
        u32 p4 = cvtpk(ht[8], ht[9]),  p5 = cvtpk(ht[10], ht[11]);
        u32 p6 = cvtpk(ht[12], ht[13]), p7 = cvtpk(ht[14], ht[15]);
        asm volatile("v_permlane32_swap_b32 %0, %1" : "+v"(p0), "+v"(p2));
        asm volatile("v_permlane32_swap_b32 %0, %1" : "+v"(p1), "+v"(p3));
        asm volatile("v_permlane32_swap_b32 %0, %1" : "+v"(p4), "+v"(p6));
        asm volatile("v_permlane32_swap_b32 %0, %1" : "+v"(p5), "+v"(p7));
        bf16x8 pa0 = pack4(p0, p1, p2, p3);
        bf16x8 pa1 = pack4(p4, p5, p6, p7);

        // ---- GEMM2: acc[ot] += pa @ W2chunk^T ----
        __builtin_amdgcn_s_setprio(1);
        #pragma unroll
        for (int ot = 0; ot < 8; ++ot) {
            bf16x8 w2f0 = *(const bf16x8*)(w2b + (hi)*4096 + (ot*32 + lo)*16);
            bf16x8 w2f1 = *(const bf16x8*)(w2b + (2 + hi)*4096 + (ot*32 + lo)*16);
            acc[ot] = __builtin_amdgcn_mfma_f32_32x32x16_bf16(pa0, w2f0, acc[ot], 0, 0, 0);
            acc[ot] = __builtin_amdgcn_mfma_f32_32x32x16_bf16(pa1, w2f1, acc[ot], 0, 0, 0);
        }
        __builtin_amdgcn_s_setprio(0);

        asm volatile("s_waitcnt vmcnt(0)" ::: "memory");
        __builtin_amdgcn_s_barrier();
        asm volatile("" ::: "memory");
    }
    #undef MSTG

    // ---- epilogue: wave-private transpose -> coalesced float4 +res stores ----
    float b2v[8];
    #pragma unroll
    for (int ot = 0; ot < 8; ++ot) b2v[ot] = B2[ot*32 + lo];

    float* scr = (float*)(lds_raw + w * 16640);   // 32 rows x 130 f32
    #pragma unroll 1
    for (int half = 0; half < 2; ++half) {
        #pragma unroll
        for (int ot4 = 0; ot4 < 4; ++ot4) {
            int ot = half*4 + ot4;
            #pragma unroll
            for (int i = 0; i < 16; ++i) {
                int r = (i & 3) + 8*(i >> 2) + 4*hi;
                scr[r*130 + ot4*32 + lo] = acc[ot][i] + b2v[ot];
            }
        }
        asm volatile("s_waitcnt lgkmcnt(0)" ::: "memory");
        __builtin_amdgcn_sched_barrier(0);
        const int rr = l >> 5, cc = (l & 31) * 4;   // full 32x128 coverage
        #pragma unroll
        for (int p = 0; p < 16; ++p) {
            float4 vv = *(const float4*)&scr[(p*2 + rr)*130 + cc];
            size_t off = (size_t)(row0 + p*2 + rr) * 256 + half*128 + cc;
            float4 rv = *(const float4*)(X + off);
            float4 ov; ov.x = vv.x + rv.x; ov.y = vv.y + rv.y;
            ov.z = vv.z + rv.z; ov.w = vv.w + rv.w;
            *(float4*)(xout + off) = ov;
        }
        asm volatile("s_waitcnt lgkmcnt(0)" ::: "memory");
        __builtin_amdgcn_sched_barrier(0);
    }
}

// ---------------- MFMA windowed attention, swapped-QK^T 32x32 ----------------
__global__ __launch_bounds__(256) void attn_kernel(
    const u16* __restrict__ qkv, const float* __restrict__ rpb,
    u16* __restrict__ outb, int shift)
{
    __shared__ u16 Vt[8][2048];       // head h: Vt[h][d*64 + (k ^ ((d&7)<<3))]
    __shared__ float biasl[8 * 176];
    __shared__ int tok[64];

    const int t = threadIdx.x;
    const int w = t >> 6;
    const int l = t & 63;
    const int lo = l & 31;
    const int hi = l >> 5;
    const int win = blockIdx.x;
    const int wj = win & 15, wi = (win >> 4) & 15, bb = win >> 8;

    if (t < 64) {
        int qq = t > 48 ? 48 : t;
        int i = div7(qq), j = qq - i*7;
        int rr = wi*7 + i + shift; if (rr >= 112) rr -= 112;
        int cc = wj*7 + j + shift; if (cc >= 112) cc -= 112;
        tok[t] = bb*12544 + rr*112 + cc;
    }
    for (int i2 = t; i2 < 1352; i2 += 256)
        biasl[(i2 & 7)*176 + (i2 >> 3)] = rpb[i2];
    __syncthreads();

    int iqv[2], jqv[2], regq[2];
    #pragma unroll
    for (int nt = 0; nt < 2; ++nt) {
        int q = nt*32 + lo; int qb = q > 48 ? 48 : q;
        int iq = div7(qb), jq = qb - iq*7;
        iqv[nt] = iq; jqv[nt] = jq;
        regq[nt] = 0;
        if (shift > 0) regq[nt] = reg3(wi*7 + iq)*3 + reg3(wj*7 + jq);
    }

    #pragma unroll 1
    for (int hh = 0; hh < 2; ++hh) {
        const int h = 2*w + hh;

        {
            u16x8 vreg[4];
            if (l < 49) {
                const u16x8* vs = (const u16x8*)(qkv + (size_t)tok[l]*768 + 512 + h*32);
                #pragma unroll
                for (int c4 = 0; c4 < 4; ++c4) vreg[c4] = vs[c4];
            } else {
                #pragma unroll
                for (int c4 = 0; c4 < 4; ++c4) vreg[c4] = (u16x8){0,0,0,0,0,0,0,0};
            }
            u16* vt = &Vt[h][0];
            #pragma unroll
            for (int c4 = 0; c4 < 4; ++c4)
                #pragma unroll
                for (int e = 0; e < 8; ++e)
                    vt[(c4*8 + e)*64 + (l ^ (e << 3))] = vreg[c4][e];
        }

        bf16x8 kf[2][2], qf[2][2];
        #pragma unroll
        for (int mt = 0; mt < 2; ++mt)
            #pragma unroll
            for (int td = 0; td < 2; ++td)
                kf[mt][td] = *(const bf16x8*)(qkv + (size_t)tok[mt*32 + lo]*768 + 256 + h*32 + td*16 + hi*8);
        #pragma unroll
        for (int nt = 0; nt < 2; ++nt)
            #pragma unroll
            for (int td = 0; td < 2; ++td)
                qf[nt][td] = *(const bf16x8*)(qkv + (size_t)tok[nt*32 + lo]*768 + h*32 + td*16 + hi*8);

        f32x16 s[2][2];
        #pragma unroll
        for (int mt = 0; mt < 2; ++mt)
            #pragma unroll
            for (int nt = 0; nt < 2; ++nt) {
                f32x16 z;
                #pragma unroll
                for (int i = 0; i < 16; ++i) z[i] = 0.f;
                s[mt][nt] = z;
            }
        #pragma unroll
        for (int td = 0; td < 2; ++td)
            #pragma unroll
            for (int mt = 0; mt < 2; ++mt)
                #pragma unroll
                for (int nt = 0; nt < 2; ++nt)
                    s[mt][nt] = __builtin_amdgcn_mfma_f32_32x32x16_bf16(kf[mt][td], qf[nt][td], s[mt][nt], 0, 0, 0);

        asm volatile("s_waitcnt lgkmcnt(0)" ::: "memory");
        __builtin_amdgcn_sched_barrier(0);

        const float* bh = biasl + h*176;
        #pragma unroll
        for (int mt = 0; mt < 2; ++mt) {
            #pragma unroll
            for (int i = 0; i < 16; ++i) {
                int r = (i & 3) + 8*(i >> 2) + 4*hi;
                int k = mt*32 + r;
                bool valid = k < 49;
                int kb = valid ? k : 48;
                int ik = div7(kb), jk = kb - ik*7;
                int regk = 0;
                if (shift > 0) regk = reg3(wi*7 + ik)*3 + reg3(wj*7 + jk);
                #pragma unroll
                for (int nt = 0; nt < 2; ++nt) {
                    float v = s[mt][nt][i] * ATTN_SCALE
                            + bh[(iqv[nt] - ik + 6)*13 + (jqv[nt] - jk + 6)];
                    if (shift > 0 && regq[nt] != regk) v -= 100.0f;
                    if (!valid) v = -1e30f;
                    s[mt][nt][i] = v;
                }
            }
        }

        #pragma unroll
        for (int nt = 0; nt < 2; ++nt) {
            float mx = -1e30f;
            #pragma unroll
            for (int i = 0; i < 16; ++i) mx = fmaxf(mx, fmaxf(s[0][nt][i], s[1][nt][i]));
            mx = fmaxf(mx, __shfl_xor(mx, 32));
            float sum = 0.f;
            #pragma unroll
            for (int mt = 0; mt < 2; ++mt)
                #pragma unroll
                for (int i = 0; i < 16; ++i) {
                    float e = __expf(s[mt][nt][i] - mx);
                    s[mt][nt][i] = e;
                    sum += e;
                }
            sum += __shfl_xor(sum, 32);
            float inv = __builtin_amdgcn_rcpf(sum);

            f32x16 o;
            #pragma unroll
            for (int i = 0; i < 16; ++i) o[i] = 0.f;
            #pragma unroll
            for (int mt = 0; mt < 2; ++mt) {
                u32 q0 = cvtpk(s[mt][nt][0]*inv,  s[mt][nt][1]*inv);
                u32 q1 = cvtpk(s[mt][nt][2]*inv,  s[mt][nt][3]*inv);
                u32 q2 = cvtpk(s[mt][nt][4]*inv,  s[mt][nt][5]*inv);
                u32 q3 = cvtpk(s[mt][nt][6]*inv,  s[mt][nt][7]*inv);
                u32 q4 = cvtpk(s[mt][nt][8]*inv,  s[mt][nt][9]*inv);
                u32 q5 = cvtpk(s[mt][nt][10]*inv, s[mt][nt][11]*inv);
                u32 q6 = cvtpk(s[mt][nt][12]*inv, s[mt][nt][13]*inv);
                u32 q7 = cvtpk(s[mt][nt][14]*inv, s[mt][nt][15]*inv);
                asm volatile("v_permlane32_swap_b32 %0, %1" : "+v"(q0), "+v"(q2));
                asm volatile("v_permlane32_swap_b32 %0, %1" : "+v"(q1), "+v"(q3));
                asm volatile("v_permlane32_swap_b32 %0, %1" : "+v"(q4), "+v"(q6));
                asm volatile("v_permlane32_swap_b32 %0, %1" : "+v"(q5), "+v"(q7));
                bf16x8 pf0 = pack4(q0, q1, q2, q3);
                bf16x8 pf1 = pack4(q4, q5, q6, q7);
                bf16x8 vb0 = *(const bf16x8*)(&Vt[h][lo*64 + (((mt*2+0)*16 + hi*8) ^ ((lo & 7) << 3))]);
                bf16x8 vb1 = *(const bf16x8*)(&Vt[h][lo*64 + (((mt*2+1)*16 + hi*8) ^ ((lo & 7) << 3))]);
                o = __builtin_amdgcn_mfma_f32_32x32x16_bf16(pf0, vb0, o, 0, 0, 0);
                o = __builtin_amdgcn_mfma_f32_32x32x16_bf16(pf1, vb1, o, 0, 0, 0);
            }

            #pragma unroll
            for (int i = 0; i < 16; ++i) {
                int q = nt*32 + (i & 3) + 8*(i >> 2) + 4*hi;
                if (q < 49)
                    outb[(size_t)tok[q]*256 + h*32 + lo] = f2bf(o[i]);
            }
        }
    }
}

// ---------------- host ----------------
extern "C" void kernel_launch(void* const* d_in, const int* in_sizes, int n_in,
                              void* d_out, int out_size, void* d_ws, size_t ws_size,
                              hipStream_t stream) {
    const float* x_in   = (const float*)d_in[0];
    const float* ln1_w  = (const float*)d_in[1];
    const float* ln1_b  = (const float*)d_in[2];
    const float* qkv_w  = (const float*)d_in[3];
    const float* qkv_b  = (const float*)d_in[4];
    const float* proj_w = (const float*)d_in[5];
    const float* proj_b = (const float*)d_in[6];
    const float* rpb    = (const float*)d_in[7];
    const float* ln2_w  = (const float*)d_in[8];
    const float* ln2_b  = (const float*)d_in[9];
    const float* mlp_w1 = (const float*)d_in[10];
    const float* mlp_b1 = (const float*)d_in[11];
    const float* mlp_w2 = (const float*)d_in[12];
    const float* mlp_b2 = (const float*)d_in[13];
    float* xout = (float*)d_out;

    char* p = (char*)d_ws;
    u16* wq = (u16*)p;  p += (size_t)2*768*256*2;
    u16* wp = (u16*)p;  p += (size_t)2*256*256*2;
    u16* w1t = (u16*)p; p += (size_t)2*1024*256*2;
    u16* w2t = (u16*)p; p += (size_t)2*256*1024*2;
    u16* buf_y   = (u16*)p; p += (size_t)T_TOK*256*2;
    u16* buf_big = (u16*)p;

    {
        int n;
        n = 2*768*256;  cvt_kernel<<<(n+255)/256, 256, 0, stream>>>(qkv_w,  wq, n);
        n = 2*256*256;  cvt_kernel<<<(n+255)/256, 256, 0, stream>>>(proj_w, wp, n);
        cvt_w1_kernel<<<2048, 256, 0, stream>>>(mlp_w1, w1t);
        cvt_w2_kernel<<<2048, 256, 0, stream>>>(mlp_w2, w2t);
    }

    for (int i = 0; i < 2; ++i) {
        const int shift = (i == 0) ? 0 : 3;
        const float* xcur = (i == 0) ? x_in : xout;

        ln_kernel<<<T_TOK/4, 256, 0, stream>>>(xcur, ln1_w + i*256, ln1_b + i*256, buf_y);
        gemm_kernel<0><<<784*6, 256, 0, stream>>>(
            buf_y, wq + (size_t)i*768*256, qkv_b + i*768, buf_big, nullptr, 768, 256, 6);
        attn_kernel<<<2048, 256, 0, stream>>>(buf_big, rpb + i*169*8, buf_y, shift);
        gemm_kernel<2><<<784*2, 256, 0, stream>>>(
            buf_y, wp + (size_t)i*256*256, proj_b + i*256, xout, xcur, 256, 256, 2);
        // fused LN2 + MLP (reads x from xout, writes xout)
        mlp_kernel<<<784, 256, 0, stream>>>(
            xout, ln2_w + i*256, ln2_b + i*256,
            w1t + (size_t)i*262144, mlp_b1 + i*1024,
            w2t + (size_t)i*262144, mlp_b2 + i*256, xout);
    }
}